// Round 1
// baseline (1576.325 us; speedup 1.0000x reference)
//
#include <hip/hip_runtime.h>

#define BB 8
#define C 64
#define CHD 32
#define HW 4096

// ---------------- fold: wvp = w_bn[:,64:] @ w_v  (64x64) ----------------
__global__ __launch_bounds__(256) void fold_kernel(const float* __restrict__ w_bn,
                                                   const float* __restrict__ w_v,
                                                   float* __restrict__ wvp) {
  int t = threadIdx.x;
#pragma unroll
  for (int i = 0; i < 16; ++i) {
    int idx = t + i * 256;          // 4096 outputs
    int o = idx >> 6, c = idx & 63;
    float acc = 0.f;
#pragma unroll
    for (int d = 0; d < 64; ++d) acc += w_bn[o * 128 + 64 + d] * w_v[d * 64 + c];
    wvp[idx] = acc;
  }
}

// ---------------- projections: xc, q, k, v' ----------------
__global__ __launch_bounds__(256) void proj_kernel(const float* __restrict__ x,
                                                   const float* __restrict__ w_cam,
                                                   const float* __restrict__ w_q,
                                                   const float* __restrict__ w_k,
                                                   const float* __restrict__ wvp,
                                                   float* __restrict__ xc,
                                                   float* __restrict__ qd,
                                                   float* __restrict__ kd,
                                                   float* __restrict__ vpd) {
  constexpr int NT = 128;
  int b = blockIdx.y;
  int n0 = blockIdx.x * NT;
  int t = threadIdx.x;
  __shared__ __align__(16) float xt[C * NT];   // [c][n] 32KB
  const float4* xg = (const float4*)(x + (size_t)b * C * HW);
  float4* xt4 = (float4*)xt;
#pragma unroll
  for (int i = 0; i < 8; ++i) {
    int idx = t + i * 256;               // 2048 f4
    int c = idx >> 5, ng = idx & 31;
    xt4[idx] = xg[c * (HW / 4) + (n0 >> 2) + ng];
  }
  __syncthreads();
  int n = t & (NT - 1);
  int h = t >> 7;                         // wave-uniform half
  float xr[C];
#pragma unroll
  for (int c = 0; c < C; ++c) xr[c] = xt[c * NT + n];

  auto do_seg = [&](const float* __restrict__ w, int rows, float* __restrict__ outp) {
    const float4* w4 = (const float4*)w;
    for (int r = 0; r < rows; ++r) {
      float acc = 0.f;
#pragma unroll
      for (int c4 = 0; c4 < 16; ++c4) {
        float4 wv = w4[r * 16 + c4];
        acc += wv.x * xr[c4 * 4] + wv.y * xr[c4 * 4 + 1] +
               wv.z * xr[c4 * 4 + 2] + wv.w * xr[c4 * 4 + 3];
      }
      outp[(size_t)r * HW + n0 + n] = acc;
    }
  };
  if (h == 0) {
    do_seg(w_cam, 64, xc + (size_t)b * C * HW);
    do_seg(w_q, 32, qd + (size_t)b * CHD * HW);
  } else {
    do_seg(w_k, 32, kd + (size_t)b * CHD * HW);
    do_seg(wvp, 64, vpd + (size_t)b * C * HW);
  }
}

// ---------------- CAM energy (split-n partials + atomics) ----------------
__global__ __launch_bounds__(256) void energy_kernel(const float* __restrict__ xc,
                                                     float* __restrict__ en) {
  int b = blockIdx.y;
  int s = blockIdx.x;                    // 0..15, 256 n each
  int t = threadIdx.x;
  int ty = t >> 4, tx = t & 15;
  __shared__ float xt[C * 129];          // pitch 129 breaks bank conflicts
  float acc[4][4] = {};
  const float4* xb4 = (const float4*)(xc + (size_t)b * C * HW);
  for (int chunk = 0; chunk < 2; ++chunk) {
    int n0 = s * 256 + chunk * 128;
    __syncthreads();
#pragma unroll
    for (int i = 0; i < 8; ++i) {
      int idx = t + i * 256;             // f4 idx, 2048
      int c = idx >> 5, ng = idx & 31;
      float4 v = xb4[c * (HW / 4) + (n0 >> 2) + ng];
      xt[c * 129 + ng * 4 + 0] = v.x;
      xt[c * 129 + ng * 4 + 1] = v.y;
      xt[c * 129 + ng * 4 + 2] = v.z;
      xt[c * 129 + ng * 4 + 3] = v.w;
    }
    __syncthreads();
    for (int n = 0; n < 128; ++n) {
      float a[4], bb[4];
#pragma unroll
      for (int i = 0; i < 4; ++i) a[i] = xt[(ty * 4 + i) * 129 + n];
#pragma unroll
      for (int j = 0; j < 4; ++j) bb[j] = xt[(tx * 4 + j) * 129 + n];
#pragma unroll
      for (int i = 0; i < 4; ++i)
#pragma unroll
        for (int j = 0; j < 4; ++j) acc[i][j] += a[i] * bb[j];
    }
  }
  float* eb = en + (size_t)b * C * C;
#pragma unroll
  for (int i = 0; i < 4; ++i)
#pragma unroll
    for (int j = 0; j < 4; ++j)
      atomicAdd(&eb[(ty * 4 + i) * C + tx * 4 + j], acc[i][j]);
}

// ---------------- CAM softmax + M1 = w_bn1 @ attn_c ----------------
__global__ __launch_bounds__(256) void cam_m1_kernel(const float* __restrict__ en,
                                                     const float* __restrict__ w_bn,
                                                     float* __restrict__ m1) {
  int b = blockIdx.x;
  int t = threadIdx.x;
  __shared__ float at[C * 65];
  if (t < 64) {
    const float* er = en + (size_t)b * C * C + t * C;
    float row[64];
    float mx = -1e30f;
#pragma unroll
    for (int d = 0; d < 64; ++d) { row[d] = er[d]; mx = fmaxf(mx, row[d]); }
    float sum = 0.f;
#pragma unroll
    for (int d = 0; d < 64; ++d) { row[d] = __expf(row[d] - mx); sum += row[d]; }
    float inv = 1.f / sum;
#pragma unroll
    for (int d = 0; d < 64; ++d) at[t * 65 + d] = row[d] * inv;
  }
  __syncthreads();
  int r = t & 63, qg = t >> 6;
  const float* wb = w_bn + r * 2 * C;    // w_bn1 row r
  float wr[64];
#pragma unroll
  for (int e = 0; e < 64; ++e) wr[e] = wb[e];
  float* mb = m1 + (size_t)b * C * C;
  for (int dc = 0; dc < 16; ++dc) {
    int d = qg * 16 + dc;
    float acc = 0.f;
#pragma unroll
    for (int e = 0; e < 64; ++e) acc += wr[e] * at[e * 65 + d];
    mb[r * C + d] = acc;
  }
}

// ---------------- SAM flash attention (fp32), V pre-folded with w_bn2 ----------------
__global__ __launch_bounds__(256) void fa_kernel(const float* __restrict__ qd,
                                                 const float* __restrict__ kd,
                                                 const float* __restrict__ vpd,
                                                 float* __restrict__ osd) {
  constexpr int QB = 64, MB = 64;
  int b = blockIdx.y;
  int n0 = blockIdx.x * QB;
  int t = threadIdx.x;
  int qr = t & 63;                        // query row in tile
  int g = t >> 6;                         // wave id: m-slots g*4.. / channels g*16..

  __shared__ __align__(16) float ks[CHD * MB];  // [ch][m]
  __shared__ __align__(16) float vs[C * MB];    // [c][m]
  __shared__ __align__(16) float ss[QB * MB];   // swizzled f4 [q][slot^q&7]

  const float* qb = qd + (size_t)b * CHD * HW + n0;
  float qreg[CHD];
#pragma unroll
  for (int ch = 0; ch < CHD; ++ch) qreg[ch] = qb[ch * HW + qr];

  float o[16];
#pragma unroll
  for (int j = 0; j < 16; ++j) o[j] = 0.f;
  float mrun = -1e30f, lrun = 0.f;

  const float4* kg = (const float4*)(kd + (size_t)b * CHD * HW);
  const float4* vg = (const float4*)(vpd + (size_t)b * C * HW);
  float4* ks4 = (float4*)ks;
  float4* vs4 = (float4*)vs;
  float4* ss4 = (float4*)ss;

#pragma unroll 1
  for (int tt = 0; tt < HW / MB; ++tt) {
    int m0f4 = tt * (MB / 4);
    __syncthreads();                      // phase2(t-1) readers done
#pragma unroll
    for (int i = 0; i < 2; ++i) {         // K tile: 512 f4
      int idx = t + i * 256;
      int ch = idx >> 4, mg = idx & 15;
      ks4[idx] = kg[ch * (HW / 4) + m0f4 + mg];
    }
#pragma unroll
    for (int i = 0; i < 4; ++i) {         // V tile: 1024 f4
      int idx = t + i * 256;
      int c = idx >> 4, mg = idx & 15;
      vs4[idx] = vg[c * (HW / 4) + m0f4 + mg];
    }
    __syncthreads();
    // ---- phase 1: S[qr][m], wave g owns m in [g*16, g*16+16) ----
#pragma unroll
    for (int j4 = 0; j4 < 4; ++j4) {
      int slot = g * 4 + j4;
      float4 acc = {0.f, 0.f, 0.f, 0.f};
#pragma unroll
      for (int ch = 0; ch < CHD; ++ch) {
        float4 kv = ks4[ch * 16 + slot];
        acc.x += qreg[ch] * kv.x; acc.y += qreg[ch] * kv.y;
        acc.z += qreg[ch] * kv.z; acc.w += qreg[ch] * kv.w;
      }
      ss4[qr * 16 + (slot ^ (qr & 7))] = acc;
    }
    __syncthreads();
    // ---- phase 2: online softmax + PV for channels [g*16, g*16+16) ----
    float p[MB];
#pragma unroll
    for (int s = 0; s < 16; ++s) {
      float4 sv = ss4[qr * 16 + (s ^ (qr & 7))];
      p[4 * s + 0] = sv.x; p[4 * s + 1] = sv.y;
      p[4 * s + 2] = sv.z; p[4 * s + 3] = sv.w;
    }
    float tmax = -1e30f;
#pragma unroll
    for (int m = 0; m < MB; ++m) tmax = fmaxf(tmax, p[m]);
    float mnew = fmaxf(mrun, tmax);
    float alpha = __expf(mrun - mnew);
    float psum = 0.f;
#pragma unroll
    for (int m = 0; m < MB; ++m) { p[m] = __expf(p[m] - mnew); psum += p[m]; }
    lrun = lrun * alpha + psum;
#pragma unroll
    for (int j = 0; j < 16; ++j) o[j] *= alpha;
    int c0 = g * 16;
#pragma unroll
    for (int j = 0; j < 16; ++j) {
      const float4* vrow = vs4 + (c0 + j) * 16;
      float acc = 0.f;
#pragma unroll
      for (int mg = 0; mg < 16; ++mg) {
        float4 vv = vrow[mg];
        acc += p[4 * mg] * vv.x + p[4 * mg + 1] * vv.y +
               p[4 * mg + 2] * vv.z + p[4 * mg + 3] * vv.w;
      }
      o[j] += acc;
    }
    mrun = mnew;
  }
  float inv = 1.f / lrun;
  float* ob = osd + (size_t)b * C * HW + n0;
#pragma unroll
  for (int j = 0; j < 16; ++j) ob[(g * 16 + j) * HW + qr] = o[j] * inv;
}

// ---------------- epilogue: out = x + M1@x + os (os already holds w_bn2-folded SAM) ----------------
__global__ __launch_bounds__(256) void final_kernel(const float* __restrict__ x,
                                                    const float* __restrict__ m1,
                                                    float* outp) {  // outp holds os, overwritten in place
  constexpr int NT = 128;
  int b = blockIdx.y;
  int n0 = blockIdx.x * NT;
  int t = threadIdx.x;
  __shared__ __align__(16) float xt[C * NT];
  __shared__ __align__(16) float ms[C * C];
  const float4* xg = (const float4*)(x + (size_t)b * C * HW);
  float4* xt4 = (float4*)xt;
#pragma unroll
  for (int i = 0; i < 8; ++i) {
    int idx = t + i * 256;
    int c = idx >> 5, ng = idx & 31;
    xt4[idx] = xg[c * (HW / 4) + (n0 >> 2) + ng];
  }
  const float4* mg4 = (const float4*)(m1 + (size_t)b * C * C);
  float4* ms4 = (float4*)ms;
#pragma unroll
  for (int i = 0; i < 4; ++i) ms4[t + i * 256] = mg4[t + i * 256];
  __syncthreads();
  int n = t & (NT - 1), h = t >> 7;
  float xr[C];
#pragma unroll
  for (int c = 0; c < C; ++c) xr[c] = xt[c * NT + n];
  float* ob = outp + (size_t)b * C * HW + n0 + n;
  for (int ci = 0; ci < 32; ++ci) {
    int c = h * 32 + ci;
    float acc = xr[c] + ob[(size_t)c * HW];   // residual + SAM part (read before write)
    const float4* mr = (const float4*)(ms + c * C);
#pragma unroll
    for (int d4 = 0; d4 < 16; ++d4) {
      float4 mv = mr[d4];
      acc += mv.x * xr[d4 * 4] + mv.y * xr[d4 * 4 + 1] +
             mv.z * xr[d4 * 4 + 2] + mv.w * xr[d4 * 4 + 3];
    }
    ob[(size_t)c * HW] = acc;
  }
}

extern "C" void kernel_launch(void* const* d_in, const int* in_sizes, int n_in,
                              void* d_out, int out_size, void* d_ws, size_t ws_size,
                              hipStream_t stream) {
  const float* x     = (const float*)d_in[0];
  const float* w_cam = (const float*)d_in[1];
  const float* w_q   = (const float*)d_in[2];
  const float* w_k   = (const float*)d_in[3];
  const float* w_v   = (const float*)d_in[4];
  const float* w_bn  = (const float*)d_in[5];
  float* out = (float*)d_out;
  float* ws  = (float*)d_ws;

  // workspace layout (floats)
  float* wvp = ws;                               // 64*64
  float* qd  = wvp + 64 * 64;                    // B*32*HW
  float* kd  = qd + (size_t)BB * CHD * HW;       // B*32*HW
  float* vpd = kd + (size_t)BB * CHD * HW;       // B*64*HW
  float* xcd = vpd + (size_t)BB * C * HW;        // B*64*HW
  float* en  = xcd + (size_t)BB * C * HW;        // B*64*64
  float* m1  = en + (size_t)BB * C * C;          // B*64*64
  // total ~25.5 MB; SAM output uses d_out as scratch

  hipMemsetAsync(en, 0, (size_t)BB * C * C * sizeof(float), stream);
  fold_kernel<<<1, 256, 0, stream>>>(w_bn, w_v, wvp);
  proj_kernel<<<dim3(HW / 128, BB), 256, 0, stream>>>(x, w_cam, w_q, w_k, wvp,
                                                      xcd, qd, kd, vpd);
  energy_kernel<<<dim3(16, BB), 256, 0, stream>>>(xcd, en);
  cam_m1_kernel<<<BB, 256, 0, stream>>>(en, w_bn, m1);
  fa_kernel<<<dim3(HW / 64, BB), 256, 0, stream>>>(qd, kd, vpd, out);
  final_kernel<<<dim3(HW / 128, BB), 256, 0, stream>>>(x, m1, out);
}

// Round 2
// 203.611 us; speedup vs baseline: 7.7419x; 7.7419x over previous
//
#include <hip/hip_runtime.h>

#define BB 8
#define C 64
#define CHD 32
#define HW 4096

typedef __attribute__((ext_vector_type(8))) __bf16 bf16x8;
typedef __attribute__((ext_vector_type(16))) float f32x16;
typedef unsigned int uint;
typedef unsigned short ushort;

__device__ __forceinline__ ushort bfb(float f) {
  return __builtin_bit_cast(ushort, (__bf16)f);
}
__device__ __forceinline__ uint pk2(float a, float b) {
  return (uint)bfb(a) | ((uint)bfb(b) << 16);
}
__device__ __forceinline__ void gload_lds16(const void* g, void* l) {
  __builtin_amdgcn_global_load_lds((const __attribute__((address_space(1))) void*)g,
                                   (__attribute__((address_space(3))) void*)l, 16, 0, 0);
}

// ---------------- fold: wvp = w_bn[:,64:] @ w_v  (64x64) ----------------
__global__ __launch_bounds__(256) void fold_kernel(const float* __restrict__ w_bn,
                                                   const float* __restrict__ w_v,
                                                   float* __restrict__ wvp) {
  int t = threadIdx.x;
#pragma unroll
  for (int i = 0; i < 16; ++i) {
    int idx = t + i * 256;
    int o = idx >> 6, c = idx & 63;
    float acc = 0.f;
#pragma unroll
    for (int d = 0; d < 64; ++d) acc += w_bn[o * 128 + 64 + d] * w_v[d * 64 + c];
    wvp[idx] = acc;
  }
}

// ---------------- projections: xc (f32), q/k/vp (bf16, baked MFMA layouts) ----------------
// qd2: byte (b*4096+n)*64 + ch*2
// kd2: byte (b*64+tt)*4096 + (mt>>5)*2048 + (ch>>4)*1024 + ((mt&31)*2+((ch>>3)&1))*16 + (ch&7)*2
// vpd2: byte (b*64+tt)*8192 + (c>>5)*4096 + ((mt>>4))*1024 + ((c&31)*2+((mt>>3)&1))*16 + (mt&7)*2
__global__ __launch_bounds__(256) void proj_kernel(const float* __restrict__ x,
                                                   const float* __restrict__ w_cam,
                                                   const float* __restrict__ w_q,
                                                   const float* __restrict__ w_k,
                                                   const float* __restrict__ wvp,
                                                   float* __restrict__ xc,
                                                   char* __restrict__ qd2,
                                                   char* __restrict__ kd2,
                                                   char* __restrict__ vpd2) {
  constexpr int NT = 128;
  constexpr float LOG2E = 1.44269504088896f;
  int b = blockIdx.y;
  int n0 = blockIdx.x * NT;
  int t = threadIdx.x;
  __shared__ __align__(16) float xt[C * NT];
  const float4* xg = (const float4*)(x + (size_t)b * C * HW);
  float4* xt4 = (float4*)xt;
#pragma unroll
  for (int i = 0; i < 8; ++i) {
    int idx = t + i * 256;
    int c = idx >> 5, ng = idx & 31;
    xt4[idx] = xg[c * (HW / 4) + (n0 >> 2) + ng];
  }
  __syncthreads();
  int n = t & (NT - 1);
  int h = t >> 7;
  int gn = n0 + n;
  float xr[C];
#pragma unroll
  for (int c = 0; c < C; ++c) xr[c] = xt[c * NT + n];

  auto dotrow = [&](const float* __restrict__ wrow) {
    const float4* w4 = (const float4*)wrow;
    float acc = 0.f;
#pragma unroll
    for (int c4 = 0; c4 < 16; ++c4) {
      float4 wv = w4[c4];
      acc += wv.x * xr[c4 * 4] + wv.y * xr[c4 * 4 + 1] +
             wv.z * xr[c4 * 4 + 2] + wv.w * xr[c4 * 4 + 3];
    }
    return acc;
  };

  if (h == 0) {
    float* xcb = xc + (size_t)b * C * HW;
    for (int r = 0; r < 64; ++r) xcb[(size_t)r * HW + gn] = dotrow(w_cam + r * 64);
    float qv[32];
    for (int r = 0; r < 32; ++r) qv[r] = LOG2E * dotrow(w_q + r * 64);
    char* qbp = qd2 + (size_t)(b * 4096 + gn) * 64;
#pragma unroll
    for (int c4 = 0; c4 < 4; ++c4) {
      uint4 w;
      w.x = pk2(qv[c4 * 8 + 0], qv[c4 * 8 + 1]);
      w.y = pk2(qv[c4 * 8 + 2], qv[c4 * 8 + 3]);
      w.z = pk2(qv[c4 * 8 + 4], qv[c4 * 8 + 5]);
      w.w = pk2(qv[c4 * 8 + 6], qv[c4 * 8 + 7]);
      *(uint4*)(qbp + c4 * 16) = w;
    }
  } else {
    int tt = gn >> 6, mt = gn & 63;
    float kvv[32];
    for (int r = 0; r < 32; ++r) kvv[r] = dotrow(w_k + r * 64);
    char* kbp = kd2 + (size_t)(b * 64 + tt) * 4096 + (mt >> 5) * 2048 + (mt & 31) * 32;
#pragma unroll
    for (int chk = 0; chk < 2; ++chk)
#pragma unroll
      for (int hb = 0; hb < 2; ++hb) {
        int base = chk * 16 + hb * 8;
        uint4 w;
        w.x = pk2(kvv[base + 0], kvv[base + 1]);
        w.y = pk2(kvv[base + 2], kvv[base + 3]);
        w.z = pk2(kvv[base + 4], kvv[base + 5]);
        w.w = pk2(kvv[base + 6], kvv[base + 7]);
        *(uint4*)(kbp + chk * 1024 + hb * 16) = w;
      }
    float vv[64];
    for (int r = 0; r < 64; ++r) vv[r] = dotrow(wvp + r * 64);
    char* vbp = vpd2 + (size_t)(b * 64 + tt) * 8192 + (mt >> 4) * 1024 +
                ((mt >> 3) & 1) * 16 + (mt & 7) * 2;
    for (int c = 0; c < 64; ++c)
      *(ushort*)(vbp + (c >> 5) * 4096 + (c & 31) * 32) = bfb(vv[c]);
  }
}

// ---------------- CAM energy (split-n partials + atomics) ----------------
__global__ __launch_bounds__(256) void energy_kernel(const float* __restrict__ xc,
                                                     float* __restrict__ en) {
  int b = blockIdx.y;
  int s = blockIdx.x;
  int t = threadIdx.x;
  int ty = t >> 4, tx = t & 15;
  __shared__ float xt[C * 129];
  float acc[4][4] = {};
  const float4* xb4 = (const float4*)(xc + (size_t)b * C * HW);
  for (int chunk = 0; chunk < 2; ++chunk) {
    int n0 = s * 256 + chunk * 128;
    __syncthreads();
#pragma unroll
    for (int i = 0; i < 8; ++i) {
      int idx = t + i * 256;
      int c = idx >> 5, ng = idx & 31;
      float4 v = xb4[c * (HW / 4) + (n0 >> 2) + ng];
      xt[c * 129 + ng * 4 + 0] = v.x;
      xt[c * 129 + ng * 4 + 1] = v.y;
      xt[c * 129 + ng * 4 + 2] = v.z;
      xt[c * 129 + ng * 4 + 3] = v.w;
    }
    __syncthreads();
    for (int nn = 0; nn < 128; ++nn) {
      float a[4], bb[4];
#pragma unroll
      for (int i = 0; i < 4; ++i) a[i] = xt[(ty * 4 + i) * 129 + nn];
#pragma unroll
      for (int j = 0; j < 4; ++j) bb[j] = xt[(tx * 4 + j) * 129 + nn];
#pragma unroll
      for (int i = 0; i < 4; ++i)
#pragma unroll
        for (int j = 0; j < 4; ++j) acc[i][j] += a[i] * bb[j];
    }
  }
  float* eb = en + (size_t)b * C * C;
#pragma unroll
  for (int i = 0; i < 4; ++i)
#pragma unroll
    for (int j = 0; j < 4; ++j)
      atomicAdd(&eb[(ty * 4 + i) * C + tx * 4 + j], acc[i][j]);
}

// ---------------- CAM softmax + M1 = w_bn1 @ attn_c ----------------
__global__ __launch_bounds__(256) void cam_m1_kernel(const float* __restrict__ en,
                                                     const float* __restrict__ w_bn,
                                                     float* __restrict__ m1) {
  int b = blockIdx.x;
  int t = threadIdx.x;
  __shared__ float at[C * 65];
  if (t < 64) {
    const float* er = en + (size_t)b * C * C + t * C;
    float row[64];
    float mx = -1e30f;
#pragma unroll
    for (int d = 0; d < 64; ++d) { row[d] = er[d]; mx = fmaxf(mx, row[d]); }
    float sum = 0.f;
#pragma unroll
    for (int d = 0; d < 64; ++d) { row[d] = __expf(row[d] - mx); sum += row[d]; }
    float inv = 1.f / sum;
#pragma unroll
    for (int d = 0; d < 64; ++d) at[t * 65 + d] = row[d] * inv;
  }
  __syncthreads();
  int r = t & 63, qg = t >> 6;
  const float* wb = w_bn + r * 2 * C;
  float wr[64];
#pragma unroll
  for (int e = 0; e < 64; ++e) wr[e] = wb[e];
  float* mb = m1 + (size_t)b * C * C;
  for (int dc = 0; dc < 16; ++dc) {
    int d = qg * 16 + dc;
    float acc = 0.f;
#pragma unroll
    for (int e = 0; e < 64; ++e) acc += wr[e] * at[e * 65 + d];
    mb[r * C + d] = acc;
  }
}

// ---------------- SAM flash attention: MFMA 32x32x16 bf16, swapped QK^T ----------------
// 4 waves: qg = wave>>1 (q-rows), kv = wave&1 (KV split, merged at end).
__global__ __launch_bounds__(256) void fa_kernel(const char* __restrict__ qd2,
                                                 const char* __restrict__ kd2,
                                                 const char* __restrict__ vpd2,
                                                 float* __restrict__ osd) {
  __shared__ __align__(16) char smem[49152];
  const int tid = threadIdx.x;
  const int lane = tid & 63;
  const int lo5 = lane & 31, hi = lane >> 5;
  const int wv = tid >> 6;
  const int qg = wv >> 1, kv = wv & 1;
  const int laneoff = lo5 * 32 + hi * 16;
  const int b = blockIdx.y;
  const int nq = blockIdx.x * 64 + qg * 32 + lo5;

  const char* qb = qd2 + (size_t)(b * 4096 + nq) * 64;
  bf16x8 qf0 = *(const bf16x8*)(qb + hi * 16);
  bf16x8 qf1 = *(const bf16x8*)(qb + 32 + hi * 16);

  f32x16 fzero;
#pragma unroll
  for (int r = 0; r < 16; ++r) fzero[r] = 0.f;
  f32x16 oacc0 = fzero, oacc1 = fzero;
  float mrun = -1e30f, lrun = 0.f;

  const size_t ktb = (size_t)(b * 64) * 4096;
  const size_t vtb = (size_t)(b * 64) * 8192;

  auto stage = [&](int iter) {  // tiles 2*iter, 2*iter+1 -> buf iter&1
    char* dstb = smem + (iter & 1) * 24576;
#pragma unroll
    for (int ss = 0; ss < 6; ++ss) {
      int s = wv * 6 + ss;
      const char* gsrc;
      char* ldst;
      if (s < 8) {
        int t2 = s >> 2, off = (s & 3) * 1024;
        gsrc = kd2 + ktb + (size_t)(2 * iter + t2) * 4096 + off;
        ldst = dstb + t2 * 12288 + off;
      } else {
        int u = s - 8;
        int t2 = u >> 3, off = (u & 7) * 1024;
        gsrc = vpd2 + vtb + (size_t)(2 * iter + t2) * 8192 + off;
        ldst = dstb + t2 * 12288 + 4096 + off;
      }
      gload_lds16(gsrc + lane * 16, ldst);
    }
  };

  stage(0);
  asm volatile("s_waitcnt vmcnt(0)" ::: "memory");
  __syncthreads();

#pragma unroll 1
  for (int i = 0; i < 32; ++i) {
    if (i < 31) stage(i + 1);
    const char* kb = smem + (i & 1) * 24576 + kv * 12288;
    const char* vb = kb + 4096;
    bf16x8 kf00 = *(const bf16x8*)(kb + laneoff);
    bf16x8 kf01 = *(const bf16x8*)(kb + 1024 + laneoff);
    bf16x8 kf10 = *(const bf16x8*)(kb + 2048 + laneoff);
    bf16x8 kf11 = *(const bf16x8*)(kb + 3072 + laneoff);
    f32x16 s0 = __builtin_amdgcn_mfma_f32_32x32x16_bf16(kf00, qf0, fzero, 0, 0, 0);
    s0 = __builtin_amdgcn_mfma_f32_32x32x16_bf16(kf01, qf1, s0, 0, 0, 0);
    f32x16 s1 = __builtin_amdgcn_mfma_f32_32x32x16_bf16(kf10, qf0, fzero, 0, 0, 0);
    s1 = __builtin_amdgcn_mfma_f32_32x32x16_bf16(kf11, qf1, s1, 0, 0, 0);
    bf16x8 vfa[4], vfb[4];
#pragma unroll
    for (int ks = 0; ks < 4; ++ks) {
      vfa[ks] = *(const bf16x8*)(vb + ks * 1024 + laneoff);
      vfb[ks] = *(const bf16x8*)(vb + 4096 + ks * 1024 + laneoff);
    }
    // ---- online softmax over m (rows of S^T), lane-local + one xor32 ----
    float tmax = -1e30f;
#pragma unroll
    for (int r = 0; r < 16; ++r) {
      tmax = fmaxf(tmax, s0[r]);
      tmax = fmaxf(tmax, s1[r]);
    }
    tmax = fmaxf(tmax, __shfl_xor(tmax, 32));
    float mnew = fmaxf(mrun, tmax);
    float alpha = __builtin_amdgcn_exp2f(mrun - mnew);
    float ps = 0.f;
#pragma unroll
    for (int r = 0; r < 16; ++r) {
      s0[r] = __builtin_amdgcn_exp2f(s0[r] - mnew);
      ps += s0[r];
    }
#pragma unroll
    for (int r = 0; r < 16; ++r) {
      s1[r] = __builtin_amdgcn_exp2f(s1[r] - mnew);
      ps += s1[r];
    }
    ps += __shfl_xor(ps, 32);
    lrun = lrun * alpha + ps;
    mrun = mnew;
#pragma unroll
    for (int r = 0; r < 16; ++r) {
      oacc0[r] *= alpha;
      oacc1[r] *= alpha;
    }
    // ---- P->bf16 B-frags (pack + xor32 swap), PV MFMAs ----
#pragma unroll
    for (int ks = 0; ks < 4; ++ks) {
      const f32x16& pm = (ks < 2) ? s0 : s1;
      const int rb = (ks & 1) * 8;
      uint w0 = pk2(pm[rb + 0], pm[rb + 1]);
      uint w1 = pk2(pm[rb + 2], pm[rb + 3]);
      uint w2 = pk2(pm[rb + 4], pm[rb + 5]);
      uint w3 = pk2(pm[rb + 6], pm[rb + 7]);
      uint x0 = __shfl_xor(w0, 32);
      uint x1 = __shfl_xor(w1, 32);
      uint x2 = __shfl_xor(w2, 32);
      uint x3 = __shfl_xor(w3, 32);
      uint4 fw;
      fw.x = hi ? x2 : w0;
      fw.y = hi ? x3 : w1;
      fw.z = hi ? w2 : x0;
      fw.w = hi ? w3 : x1;
      bf16x8 pf = __builtin_bit_cast(bf16x8, fw);
      oacc0 = __builtin_amdgcn_mfma_f32_32x32x16_bf16(vfa[ks], pf, oacc0, 0, 0, 0);
      oacc1 = __builtin_amdgcn_mfma_f32_32x32x16_bf16(vfb[ks], pf, oacc1, 0, 0, 0);
    }
    asm volatile("s_waitcnt vmcnt(0)" ::: "memory");
    __syncthreads();
  }

  // ---- merge the two KV-split waves per q-group ----
  float* mlb = (float*)smem;            // [2][64][2]
  float* ob = (float*)(smem + 1024);    // [2][64][33] padded
  if (kv == 1) {
    float* mp = mlb + (qg * 64 + lane) * 2;
    mp[0] = mrun;
    mp[1] = lrun;
    float* op = ob + (qg * 64 + lane) * 33;
#pragma unroll
    for (int r = 0; r < 16; ++r) {
      op[r] = oacc0[r];
      op[16 + r] = oacc1[r];
    }
  }
  __syncthreads();
  if (kv == 0) {
    const float* mp = mlb + (qg * 64 + lane) * 2;
    float m2 = mp[0], l2 = mp[1];
    const float* op = ob + (qg * 64 + lane) * 33;
    float mstar = fmaxf(mrun, m2);
    float a1 = __builtin_amdgcn_exp2f(mrun - mstar);
    float a2 = __builtin_amdgcn_exp2f(m2 - mstar);
    float linv = 1.f / (lrun * a1 + l2 * a2);
    float* outb = osd + (size_t)b * C * HW + blockIdx.x * 64 + qg * 32 + lo5;
#pragma unroll
    for (int r = 0; r < 16; ++r) {
      int c0 = (r & 3) + 8 * (r >> 2) + 4 * hi;
      outb[(size_t)c0 * HW] = (oacc0[r] * a1 + op[r] * a2) * linv;
      outb[(size_t)(32 + c0) * HW] = (oacc1[r] * a1 + op[16 + r] * a2) * linv;
    }
  }
}

// ---------------- epilogue: out = x + M1@x + os ----------------
__global__ __launch_bounds__(256) void final_kernel(const float* __restrict__ x,
                                                    const float* __restrict__ m1,
                                                    float* outp) {
  constexpr int NT = 128;
  int b = blockIdx.y;
  int n0 = blockIdx.x * NT;
  int t = threadIdx.x;
  __shared__ __align__(16) float xt[C * NT];
  __shared__ __align__(16) float ms[C * C];
  const float4* xg = (const float4*)(x + (size_t)b * C * HW);
  float4* xt4 = (float4*)xt;
#pragma unroll
  for (int i = 0; i < 8; ++i) {
    int idx = t + i * 256;
    int c = idx >> 5, ng = idx & 31;
    xt4[idx] = xg[c * (HW / 4) + (n0 >> 2) + ng];
  }
  const float4* mg4 = (const float4*)(m1 + (size_t)b * C * C);
  float4* ms4 = (float4*)ms;
#pragma unroll
  for (int i = 0; i < 4; ++i) ms4[t + i * 256] = mg4[t + i * 256];
  __syncthreads();
  int n = t & (NT - 1), h = t >> 7;
  float xr[C];
#pragma unroll
  for (int c = 0; c < C; ++c) xr[c] = xt[c * NT + n];
  float* obp = outp + (size_t)b * C * HW + n0 + n;
  for (int ci = 0; ci < 32; ++ci) {
    int c = h * 32 + ci;
    float acc = xr[c] + obp[(size_t)c * HW];
    const float4* mr = (const float4*)(ms + c * C);
#pragma unroll
    for (int d4 = 0; d4 < 16; ++d4) {
      float4 mv = mr[d4];
      acc += mv.x * xr[d4 * 4] + mv.y * xr[d4 * 4 + 1] +
             mv.z * xr[d4 * 4 + 2] + mv.w * xr[d4 * 4 + 3];
    }
    obp[(size_t)c * HW] = acc;
  }
}

extern "C" void kernel_launch(void* const* d_in, const int* in_sizes, int n_in,
                              void* d_out, int out_size, void* d_ws, size_t ws_size,
                              hipStream_t stream) {
  const float* x     = (const float*)d_in[0];
  const float* w_cam = (const float*)d_in[1];
  const float* w_q   = (const float*)d_in[2];
  const float* w_k   = (const float*)d_in[3];
  const float* w_v   = (const float*)d_in[4];
  const float* w_bn  = (const float*)d_in[5];
  float* out = (float*)d_out;
  char* wsb = (char*)d_ws;

  // workspace layout (bytes), all 16B-aligned
  float* wvp = (float*)wsb;                          // 16 KB (64*64 f32)
  float* xcd = (float*)(wsb + 16384);                // 8 MB
  float* en  = (float*)(wsb + 16384 + 8388608);      // 128 KB
  float* m1  = (float*)(wsb + 16384 + 8388608 + 131072);  // 128 KB
  char* qd2  = wsb + 16384 + 8388608 + 131072 + 131072;   // 2 MB bf16
  char* kd2  = qd2 + 2097152;                        // 2 MB bf16
  char* vpd2 = kd2 + 2097152;                        // 4 MB bf16

  hipMemsetAsync(en, 0, (size_t)BB * C * C * sizeof(float), stream);
  fold_kernel<<<1, 256, 0, stream>>>(w_bn, w_v, wvp);
  proj_kernel<<<dim3(HW / 128, BB), 256, 0, stream>>>(x, w_cam, w_q, w_k, wvp,
                                                      xcd, qd2, kd2, vpd2);
  energy_kernel<<<dim3(16, BB), 256, 0, stream>>>(xcd, en);
  cam_m1_kernel<<<BB, 256, 0, stream>>>(en, w_bn, m1);
  fa_kernel<<<dim3(HW / 64, BB), 256, 0, stream>>>(qd2, kd2, vpd2, out);
  final_kernel<<<dim3(HW / 128, BB), 256, 0, stream>>>(x, m1, out);
}

// Round 3
// 165.101 us; speedup vs baseline: 9.5477x; 1.2333x over previous
//
#include <hip/hip_runtime.h>

#define BB 8
#define C 64
#define CHD 32
#define HW 4096

typedef __attribute__((ext_vector_type(8))) __bf16 bf16x8;
typedef __attribute__((ext_vector_type(16))) float f32x16;
typedef unsigned int uint;
typedef unsigned short ushort;

__device__ __forceinline__ ushort bfb(float f) {
  return __builtin_bit_cast(ushort, (__bf16)f);
}
__device__ __forceinline__ uint pk2(float a, float b) {
  return (uint)bfb(a) | ((uint)bfb(b) << 16);
}
__device__ __forceinline__ uint cvtpk(float a, float b) {
  uint r;
  asm("v_cvt_pk_bf16_f32 %0, %1, %2" : "=v"(r) : "v"(a), "v"(b));
  return r;
}
__device__ __forceinline__ void gload_lds16(const void* g, void* l) {
  __builtin_amdgcn_global_load_lds((const __attribute__((address_space(1))) void*)g,
                                   (__attribute__((address_space(3))) void*)l, 16, 0, 0);
}

// ---------------- fold: wvp = w_bn[:,64:] @ w_v  (64x64) ----------------
__global__ __launch_bounds__(256) void fold_kernel(const float* __restrict__ w_bn,
                                                   const float* __restrict__ w_v,
                                                   float* __restrict__ wvp) {
  int t = threadIdx.x;
#pragma unroll
  for (int i = 0; i < 16; ++i) {
    int idx = t + i * 256;
    int o = idx >> 6, c = idx & 63;
    float acc = 0.f;
#pragma unroll
    for (int d = 0; d < 64; ++d) acc += w_bn[o * 128 + 64 + d] * w_v[d * 64 + c];
    wvp[idx] = acc;
  }
}

// ---------------- prep: q/k/vp (bf16, MFMA-baked layouts) + Gram G = X X^T ----------------
// qd2:  byte (b*4096+n)*64 + ch*2
// kd2:  per (b,tt) 4KB tile: (mt>>5)*2048 + (ch>>4)*1024 + ((ch>>3)&1)*512 + (mt&31)*16 + (ch&7)*2
// vpd2: per (b,tt) 8KB tile: (c*128 + mt*2) ^ ((c&7)<<4)
__global__ __launch_bounds__(256) void prep_kernel(const float* __restrict__ x,
                                                   const float* __restrict__ w_q,
                                                   const float* __restrict__ w_k,
                                                   const float* __restrict__ wvp,
                                                   char* __restrict__ qd2,
                                                   char* __restrict__ kd2,
                                                   char* __restrict__ vpd2,
                                                   float* __restrict__ G) {
  __shared__ __align__(16) float xt[64 * 64];     // f4-chunk XOR swizzled
  __shared__ __align__(16) float wls[128 * 64];   // wq | wk | wvp
  const int b = blockIdx.y, tt = blockIdx.x, t = threadIdx.x;
  const float4* xg = (const float4*)(x + (size_t)b * C * HW);
  float4* xt4 = (float4*)xt;
#pragma unroll
  for (int i = 0; i < 4; ++i) {
    int idx = t + i * 256;
    int c = idx >> 4, ng = idx & 15;
    xt4[c * 16 + (ng ^ (c & 15))] = xg[c * 1024 + tt * 16 + ng];
  }
  float4* wl4 = (float4*)wls;
  const float4* wq4 = (const float4*)w_q;
  const float4* wk4 = (const float4*)w_k;
  const float4* wv4 = (const float4*)wvp;
#pragma unroll
  for (int i = 0; i < 2; ++i) wl4[t + i * 256] = wq4[t + i * 256];
#pragma unroll
  for (int i = 0; i < 2; ++i) wl4[512 + t + i * 256] = wk4[t + i * 256];
#pragma unroll
  for (int i = 0; i < 4; ++i) wl4[1024 + t + i * 256] = wv4[t + i * 256];
  __syncthreads();
  const int n = t & 63, sub = t >> 6;
  float xr[64];
#pragma unroll
  for (int c = 0; c < 64; ++c)
    xr[c] = xt[c * 64 + (((n >> 2) ^ (c & 15)) << 2) + (n & 3)];

  auto dotf = [&](int wbase) {
    const float4* w4 = (const float4*)(wls + wbase);
    float acc = 0.f;
#pragma unroll
    for (int c4 = 0; c4 < 16; ++c4) {
      float4 wv = w4[c4];
      acc += wv.x * xr[c4 * 4] + wv.y * xr[c4 * 4 + 1] +
             wv.z * xr[c4 * 4 + 2] + wv.w * xr[c4 * 4 + 3];
    }
    return acc;
  };

  if (sub == 0) {
    constexpr float LOG2E = 1.44269504088896f;
    float qv[32];
    for (int r = 0; r < 32; ++r) qv[r] = LOG2E * dotf(r * 64);
    char* qbp = qd2 + ((size_t)b * HW + tt * 64 + n) * 64;
#pragma unroll
    for (int c4 = 0; c4 < 4; ++c4) {
      uint4 w;
      w.x = pk2(qv[c4 * 8 + 0], qv[c4 * 8 + 1]);
      w.y = pk2(qv[c4 * 8 + 2], qv[c4 * 8 + 3]);
      w.z = pk2(qv[c4 * 8 + 4], qv[c4 * 8 + 5]);
      w.w = pk2(qv[c4 * 8 + 6], qv[c4 * 8 + 7]);
      *(uint4*)(qbp + c4 * 16) = w;
    }
  } else if (sub == 1) {
    float kv[32];
    for (int r = 0; r < 32; ++r) kv[r] = dotf(2048 + r * 64);
    char* kbp = kd2 + ((size_t)(b * 64) + tt) * 4096 + (n >> 5) * 2048 + (n & 31) * 16;
#pragma unroll
    for (int cb = 0; cb < 2; ++cb)
#pragma unroll
      for (int hb = 0; hb < 2; ++hb) {
        int base = cb * 16 + hb * 8;
        uint4 w;
        w.x = pk2(kv[base + 0], kv[base + 1]);
        w.y = pk2(kv[base + 2], kv[base + 3]);
        w.z = pk2(kv[base + 4], kv[base + 5]);
        w.w = pk2(kv[base + 6], kv[base + 7]);
        *(uint4*)(kbp + cb * 1024 + hb * 512) = w;
      }
  } else {
    int c0 = (sub - 2) * 32;
    char* vbp = vpd2 + ((size_t)(b * 64) + tt) * 8192;
    for (int r = 0; r < 32; ++r) {
      int c = c0 + r;
      float v = dotf(4096 + c * 64);
      *(ushort*)(vbp + ((c * 128 + n * 2) ^ ((c & 7) << 4))) = bfb(v);
    }
  }

  // ---- Gram partial: G[b] += xt @ xt^T ----
  const int ty = t >> 4, tx = t & 15;
  float ga[4][4] = {};
#pragma unroll
  for (int ng = 0; ng < 16; ++ng) {
    float4 a[4], bb[4];
#pragma unroll
    for (int i = 0; i < 4; ++i)
      a[i] = xt4[(ty * 4 + i) * 16 + (ng ^ ((ty * 4 + i) & 15))];
#pragma unroll
    for (int j = 0; j < 4; ++j)
      bb[j] = xt4[(tx * 4 + j) * 16 + (ng ^ ((tx * 4 + j) & 15))];
#pragma unroll
    for (int i = 0; i < 4; ++i)
#pragma unroll
      for (int j = 0; j < 4; ++j)
        ga[i][j] += a[i].x * bb[j].x + a[i].y * bb[j].y +
                    a[i].z * bb[j].z + a[i].w * bb[j].w;
  }
  float* Gb = G + (size_t)b * 4096;
#pragma unroll
  for (int i = 0; i < 4; ++i)
#pragma unroll
    for (int j = 0; j < 4; ++j)
      atomicAdd(&Gb[(ty * 4 + i) * 64 + tx * 4 + j], ga[i][j]);
}

// ---------------- CAM: E = Wc G Wc^T, softmax, M1 = w_bn1 @ attn (stored [d][o]) ----------------
__global__ __launch_bounds__(256) void cam_m1_kernel(const float* __restrict__ G,
                                                     const float* __restrict__ w_cam,
                                                     const float* __restrict__ w_bn,
                                                     float* __restrict__ m1) {
  __shared__ float gs[4096];   // G, then E
  __shared__ float ts[4096];   // T1 = Wc G
  __shared__ float wcs[4096];  // Wc, then attn
  __shared__ float wts[4096];  // Wc^T, then w_bn1^T
  const int b = blockIdx.x, t = threadIdx.x;
  float4* g4 = (float4*)gs;
  const float4* Gg = (const float4*)(G + (size_t)b * 4096);
#pragma unroll
  for (int i = 0; i < 4; ++i) g4[t + i * 256] = Gg[t + i * 256];
  float4* wcl = (float4*)wcs;
  const float4* wc4 = (const float4*)w_cam;
#pragma unroll
  for (int i = 0; i < 4; ++i) wcl[t + i * 256] = wc4[t + i * 256];
  __syncthreads();
#pragma unroll
  for (int i = 0; i < 16; ++i) {
    int idx = t + i * 256;
    int r = idx >> 6, d = idx & 63;
    wts[d * 64 + r] = wcs[r * 64 + d];
  }
  __syncthreads();
  const int lane = t & 63, rg = (t >> 6) * 16;
  float acc[16];
#pragma unroll
  for (int r = 0; r < 16; ++r) acc[r] = 0.f;
  for (int c = 0; c < 64; ++c) {
    float g = gs[c * 64 + lane];
#pragma unroll
    for (int r = 0; r < 16; ++r) acc[r] += wcs[(rg + r) * 64 + c] * g;
  }
#pragma unroll
  for (int r = 0; r < 16; ++r) ts[(rg + r) * 64 + lane] = acc[r];
  __syncthreads();
#pragma unroll
  for (int r = 0; r < 16; ++r) acc[r] = 0.f;
  for (int d = 0; d < 64; ++d) {
    float w = wts[d * 64 + lane];
#pragma unroll
    for (int r = 0; r < 16; ++r) acc[r] += ts[(rg + r) * 64 + d] * w;
  }
#pragma unroll
  for (int r = 0; r < 16; ++r) gs[(rg + r) * 64 + lane] = acc[r];
  __syncthreads();
  if (t < 64) {
    float row[64], mx = -1e30f;
#pragma unroll
    for (int d = 0; d < 64; ++d) { row[d] = gs[t * 64 + d]; mx = fmaxf(mx, row[d]); }
    float sum = 0.f;
#pragma unroll
    for (int d = 0; d < 64; ++d) { row[d] = __expf(row[d] - mx); sum += row[d]; }
    float inv = 1.f / sum;
#pragma unroll
    for (int d = 0; d < 64; ++d) wcs[t * 64 + d] = row[d] * inv;
  }
#pragma unroll
  for (int i = 0; i < 16; ++i) {
    int idx = t + i * 256;
    int o = idx & 63, r = idx >> 6;
    wts[r * 64 + o] = w_bn[o * 128 + r];
  }
  __syncthreads();
  float a2[16];
#pragma unroll
  for (int dd = 0; dd < 16; ++dd) a2[dd] = 0.f;
  for (int r = 0; r < 64; ++r) {
    float wv = wts[r * 64 + lane];
#pragma unroll
    for (int dd = 0; dd < 16; ++dd) a2[dd] += wv * wcs[r * 64 + rg + dd];
  }
  float* mb = m1 + (size_t)b * 4096;
#pragma unroll
  for (int dd = 0; dd < 16; ++dd) mb[(rg + dd) * 64 + lane] = a2[dd];
}

// ---------------- SAM flash attention: no-max exp2 softmax (bounded scores) ----------------
__global__ __launch_bounds__(256) void fa_kernel(const char* __restrict__ qd2,
                                                 const char* __restrict__ kd2,
                                                 const char* __restrict__ vpd2,
                                                 float* __restrict__ osd) {
  __shared__ __align__(16) char smem[49152];
  const int tid = threadIdx.x;
  const int lane = tid & 63;
  const int lo5 = lane & 31, hi = lane >> 5;
  const int wv = tid >> 6;
  const int qg = wv >> 1, kv = wv & 1;
  const int b = blockIdx.y;
  const int nq = blockIdx.x * 64 + qg * 32 + lo5;

  const char* qb = qd2 + ((size_t)b * HW + nq) * 64;
  bf16x8 qf0 = *(const bf16x8*)(qb + hi * 16);
  bf16x8 qf1 = *(const bf16x8*)(qb + 32 + hi * 16);

  f32x16 fzero;
#pragma unroll
  for (int r = 0; r < 16; ++r) fzero[r] = 0.f;
  f32x16 oacc0 = fzero, oacc1 = fzero;
  float lrun = 0.f;

  const size_t ktb = (size_t)(b * 64) * 4096;
  const size_t vtb = (size_t)(b * 64) * 8192;
  const int vsw = (lo5 * 128 + hi * 16) ^ ((lo5 & 7) << 4);

  auto stage = [&](int iter) {
    char* dstb = smem + (iter & 1) * 24576;
#pragma unroll
    for (int ss = 0; ss < 6; ++ss) {
      int s = wv * 6 + ss;
      const char* gsrc;
      char* ldst;
      if (s < 8) {
        int t2 = s >> 2, off = (s & 3) * 1024;
        gsrc = kd2 + ktb + (size_t)(2 * iter + t2) * 4096 + off;
        ldst = dstb + t2 * 12288 + off;
      } else {
        int u = s - 8;
        int t2 = u >> 3, off = (u & 7) * 1024;
        gsrc = vpd2 + vtb + (size_t)(2 * iter + t2) * 8192 + off;
        ldst = dstb + t2 * 12288 + 4096 + off;
      }
      gload_lds16(gsrc + lane * 16, ldst);
    }
  };

  stage(0);
  asm volatile("s_waitcnt vmcnt(0)" ::: "memory");
  __syncthreads();

#pragma unroll 1
  for (int i = 0; i < 32; ++i) {
    if (i < 31) stage(i + 1);
    const char* kb = smem + (i & 1) * 24576 + kv * 12288;
    const char* vb = kb + 4096;
    bf16x8 kf00 = *(const bf16x8*)(kb + lane * 16);
    bf16x8 kf01 = *(const bf16x8*)(kb + 1024 + lane * 16);
    bf16x8 kf10 = *(const bf16x8*)(kb + 2048 + lane * 16);
    bf16x8 kf11 = *(const bf16x8*)(kb + 3072 + lane * 16);
    f32x16 s0 = __builtin_amdgcn_mfma_f32_32x32x16_bf16(kf00, qf0, fzero, 0, 0, 0);
    s0 = __builtin_amdgcn_mfma_f32_32x32x16_bf16(kf01, qf1, s0, 0, 0, 0);
    f32x16 s1 = __builtin_amdgcn_mfma_f32_32x32x16_bf16(kf10, qf0, fzero, 0, 0, 0);
    s1 = __builtin_amdgcn_mfma_f32_32x32x16_bf16(kf11, qf1, s1, 0, 0, 0);
    bf16x8 vfa[4], vfb[4];
#pragma unroll
    for (int ks = 0; ks < 4; ++ks) {
      vfa[ks] = *(const bf16x8*)(vb + (vsw ^ (ks << 5)));
      vfb[ks] = *(const bf16x8*)(vb + 4096 + (vsw ^ (ks << 5)));
    }
    float ps = 0.f;
#pragma unroll
    for (int r = 0; r < 16; ++r) {
      s0[r] = __builtin_amdgcn_exp2f(s0[r]);
      ps += s0[r];
    }
#pragma unroll
    for (int r = 0; r < 16; ++r) {
      s1[r] = __builtin_amdgcn_exp2f(s1[r]);
      ps += s1[r];
    }
    ps += __shfl_xor(ps, 32);
    lrun += ps;
#pragma unroll
    for (int ks = 0; ks < 4; ++ks) {
      const f32x16& pm = (ks < 2) ? s0 : s1;
      const int rb = (ks & 1) * 8;
      uint w0 = cvtpk(pm[rb + 0], pm[rb + 1]);
      uint w1 = cvtpk(pm[rb + 2], pm[rb + 3]);
      uint w2 = cvtpk(pm[rb + 4], pm[rb + 5]);
      uint w3 = cvtpk(pm[rb + 6], pm[rb + 7]);
      uint x0 = __shfl_xor(w0, 32);
      uint x1 = __shfl_xor(w1, 32);
      uint x2 = __shfl_xor(w2, 32);
      uint x3 = __shfl_xor(w3, 32);
      uint4 fw;
      fw.x = hi ? x2 : w0;
      fw.y = hi ? x3 : w1;
      fw.z = hi ? w2 : x0;
      fw.w = hi ? w3 : x1;
      bf16x8 pf = __builtin_bit_cast(bf16x8, fw);
      oacc0 = __builtin_amdgcn_mfma_f32_32x32x16_bf16(vfa[ks], pf, oacc0, 0, 0, 0);
      oacc1 = __builtin_amdgcn_mfma_f32_32x32x16_bf16(vfb[ks], pf, oacc1, 0, 0, 0);
    }
    asm volatile("s_waitcnt vmcnt(0)" ::: "memory");
    __syncthreads();
  }

  float* mlb = (float*)smem;
  float* ob = (float*)(smem + 1024);
  if (kv == 1) {
    mlb[qg * 64 + lane] = lrun;
    float* op = ob + (qg * 64 + lane) * 33;
#pragma unroll
    for (int r = 0; r < 16; ++r) {
      op[r] = oacc0[r];
      op[16 + r] = oacc1[r];
    }
  }
  __syncthreads();
  if (kv == 0) {
    float l2 = mlb[qg * 64 + lane];
    const float* op = ob + (qg * 64 + lane) * 33;
    float linv = 1.f / (lrun + l2);
    float* outb = osd + (size_t)b * C * HW + blockIdx.x * 64 + qg * 32 + lo5;
#pragma unroll
    for (int r = 0; r < 16; ++r) {
      int c0 = (r & 3) + 8 * (r >> 2) + 4 * hi;
      outb[(size_t)c0 * HW] = (oacc0[r] + op[r]) * linv;
      outb[(size_t)(32 + c0) * HW] = (oacc1[r] + op[16 + r]) * linv;
    }
  }
}

// ---------------- epilogue: out = x + M1@x + os ----------------
__global__ __launch_bounds__(256) void final_kernel(const float* __restrict__ x,
                                                    const float* __restrict__ m1,
                                                    float* __restrict__ outp) {
  __shared__ __align__(16) float xt[64 * 64];
  __shared__ __align__(16) float ms[64 * 64];  // [d][c]
  const int b = blockIdx.y, tt = blockIdx.x, t = threadIdx.x;
  const float4* xg = (const float4*)(x + (size_t)b * C * HW);
  float4* xt4 = (float4*)xt;
#pragma unroll
  for (int i = 0; i < 4; ++i) {
    int idx = t + i * 256;
    int c = idx >> 4, ng = idx & 15;
    xt4[c * 16 + (ng ^ (c & 15))] = xg[c * 1024 + tt * 16 + ng];
  }
  float4* ms4 = (float4*)ms;
  const float4* mg = (const float4*)(m1 + (size_t)b * 4096);
#pragma unroll
  for (int i = 0; i < 4; ++i) ms4[t + i * 256] = mg[t + i * 256];
  __syncthreads();
  const int n = t & 63, sub = t >> 6;
  float xr[64];
#pragma unroll
  for (int c = 0; c < 64; ++c)
    xr[c] = xt[c * 64 + (((n >> 2) ^ (c & 15)) << 2) + (n & 3)];
  float* ob = outp + (size_t)b * C * HW + tt * 64 + n;
  float acc[16];
#pragma unroll
  for (int ci = 0; ci < 16; ++ci)
    acc[ci] = xr[sub * 16 + ci] + ob[(size_t)(sub * 16 + ci) * HW];
  for (int d = 0; d < 64; ++d) {
    float xv = xr[d];
    const float4* mr = (const float4*)(ms + d * 64 + sub * 16);
#pragma unroll
    for (int c4 = 0; c4 < 4; ++c4) {
      float4 mv = mr[c4];
      acc[c4 * 4 + 0] += mv.x * xv;
      acc[c4 * 4 + 1] += mv.y * xv;
      acc[c4 * 4 + 2] += mv.z * xv;
      acc[c4 * 4 + 3] += mv.w * xv;
    }
  }
#pragma unroll
  for (int ci = 0; ci < 16; ++ci)
    ob[(size_t)(sub * 16 + ci) * HW] = acc[ci];
}

extern "C" void kernel_launch(void* const* d_in, const int* in_sizes, int n_in,
                              void* d_out, int out_size, void* d_ws, size_t ws_size,
                              hipStream_t stream) {
  const float* x     = (const float*)d_in[0];
  const float* w_cam = (const float*)d_in[1];
  const float* w_q   = (const float*)d_in[2];
  const float* w_k   = (const float*)d_in[3];
  const float* w_v   = (const float*)d_in[4];
  const float* w_bn  = (const float*)d_in[5];
  float* out = (float*)d_out;
  char* wsb = (char*)d_ws;

  float* wvp = (float*)wsb;                              // 16 KB
  float* G   = (float*)(wsb + 16384);                    // 128 KB
  float* m1  = (float*)(wsb + 16384 + 131072);           // 128 KB
  char* qd2  = wsb + 16384 + 131072 + 131072;            // 2 MB
  char* kd2  = qd2 + 2097152;                            // 2 MB
  char* vpd2 = kd2 + 2097152;                            // 4 MB

  hipMemsetAsync(G, 0, (size_t)BB * 4096 * sizeof(float), stream);
  fold_kernel<<<1, 256, 0, stream>>>(w_bn, w_v, wvp);
  prep_kernel<<<dim3(64, BB), 256, 0, stream>>>(x, w_q, w_k, wvp, qd2, kd2, vpd2, G);
  cam_m1_kernel<<<BB, 256, 0, stream>>>(G, w_cam, w_bn, m1);
  fa_kernel<<<dim3(HW / 64, BB), 256, 0, stream>>>(qd2, kd2, vpd2, out);
  final_kernel<<<dim3(64, BB), 256, 0, stream>>>(x, m1, out);
}

// Round 5
// 131.666 us; speedup vs baseline: 11.9721x; 1.2539x over previous
//
#include <hip/hip_runtime.h>

#define BB 8
#define C 64
#define HW 4096

typedef __attribute__((ext_vector_type(8))) __bf16 bf16x8;
typedef __attribute__((ext_vector_type(16))) float f32x16;
typedef unsigned int uint;
typedef unsigned short ushort;

__device__ __forceinline__ ushort bfb(float f) {
  return __builtin_bit_cast(ushort, (__bf16)f);
}
__device__ __forceinline__ uint pk2(float a, float b) {
  return (uint)bfb(a) | ((uint)bfb(b) << 16);
}
__device__ __forceinline__ uint cvtpk(float a, float b) {
  uint r;
  asm("v_cvt_pk_bf16_f32 %0, %1, %2" : "=v"(r) : "v"(a), "v"(b));
  return r;
}
__device__ __forceinline__ void gload_lds16(const void* g, void* l) {
  __builtin_amdgcn_global_load_lds((const __attribute__((address_space(1))) void*)g,
                                   (__attribute__((address_space(3))) void*)l, 16, 0, 0);
}
__device__ __forceinline__ f32x16 mfma_bf16(bf16x8 a, bf16x8 b, f32x16 c) {
  return __builtin_amdgcn_mfma_f32_32x32x16_bf16(a, b, c, 0, 0, 0);
}

// ---------------- fold: build wall A/B fragments for {q*log2e, k, wvp} ----------------
__global__ __launch_bounds__(64) void fold_kernel(const float* __restrict__ w_bn,
                                                  const float* __restrict__ w_q,
                                                  const float* __restrict__ w_k,
                                                  const float* __restrict__ w_v,
                                                  char* __restrict__ wall) {
  const int slot = blockIdx.x;         // ot*4 + kc
  const int ot = slot >> 2, kc = slot & 3;
  const int l = threadIdx.x, lo5 = l & 31, hi = l >> 5;
  float v[8];
  if (ot == 0) {
#pragma unroll
    for (int j = 0; j < 8; ++j)
      v[j] = 1.44269504088896f * w_q[lo5 * 64 + kc * 16 + hi * 8 + j];
  } else if (ot == 1) {
#pragma unroll
    for (int j = 0; j < 8; ++j) v[j] = w_k[lo5 * 64 + kc * 16 + hi * 8 + j];
  } else {
    int c = (ot - 2) * 32 + lo5;
#pragma unroll
    for (int j = 0; j < 8; ++j) {
      int d = kc * 16 + hi * 8 + j;
      float acc = 0.f;
      for (int e = 0; e < 64; ++e) acc += w_bn[c * 128 + 64 + e] * w_v[e * 64 + d];
      v[j] = acc;
    }
  }
  uint4 w;
  w.x = pk2(v[0], v[1]); w.y = pk2(v[2], v[3]);
  w.z = pk2(v[4], v[5]); w.w = pk2(v[6], v[7]);
  *(uint4*)(wall + slot * 1024 + l * 16) = w;
}

// ---------------- prep: q/k/vp via MFMA, outputs in exact fa fragment layouts ----------------
// qd2:  [b][n][ch] bf16 (64B per n)
// kd2:  per (b,tt) 4KB: (m>>5)*2048 + (ch>>3)*512 + (m&31)*16 + (ch&7)*2
// vpd2: per (b,tt) 8KB: (c>>5)*4096 + (m>>3)*512 + (c&31)*16 + (m&7)*2
__global__ __launch_bounds__(128) void prep_kernel(const float* __restrict__ x,
                                                   const char* __restrict__ wall,
                                                   char* __restrict__ qd2,
                                                   char* __restrict__ kd2,
                                                   char* __restrict__ vpd2) {
  const int bx = blockIdx.x;
  const int b = bx >> 6, nt = bx & 63;
  const int t = threadIdx.x;
  const int wv = t >> 6, l = t & 63, lo5 = l & 31, hi = l >> 5;
  const int n0 = nt * 64 + wv * 32;
  const int tt = nt;
  const int n = n0 + lo5;
  const float* xb = x + (size_t)b * C * HW;

  f32x16 fz;
#pragma unroll
  for (int r = 0; r < 16; ++r) fz[r] = 0.f;

  // X fragments: lane -> n (A-row / B-col), k = channel d
  bf16x8 xf[4];
#pragma unroll
  for (int kc = 0; kc < 4; ++kc) {
    float xv[8];
#pragma unroll
    for (int j = 0; j < 8; ++j)
      xv[j] = xb[(size_t)(kc * 16 + hi * 8 + j) * HW + n];
    uint4 u;
    u.x = cvtpk(xv[0], xv[1]); u.y = cvtpk(xv[2], xv[3]);
    u.z = cvtpk(xv[4], xv[5]); u.w = cvtpk(xv[6], xv[7]);
    xf[kc] = __builtin_bit_cast(bf16x8, u);
  }

#pragma unroll
  for (int ot = 0; ot < 4; ++ot) {
    f32x16 acc = fz;
#pragma unroll
    for (int kc = 0; kc < 4; ++kc) {
      bf16x8 wf = *(const bf16x8*)(wall + ((ot << 2) | kc) * 1024 + l * 16);
      acc = (ot < 2) ? mfma_bf16(wf, xf[kc], acc)    // D[col=n][row=out]
                     : mfma_bf16(xf[kc], wf, acc);   // D[col=c][row=m]
    }
    // extract pairs: wlo = pair from hi=0 lane (row offset +0), whi = from hi=1 (+4)
    uint wlo[8], whi[8];
#pragma unroll
    for (int i2 = 0; i2 < 8; ++i2) {
      uint w = cvtpk(acc[2 * i2], acc[2 * i2 + 1]);
      uint p = __shfl_xor(w, 32);
      wlo[i2] = hi ? p : w;
      whi[i2] = hi ? w : p;
    }
    uint4 u40, u41;
    u40.x = hi ? wlo[4] : wlo[0];
    u40.y = hi ? wlo[5] : wlo[1];
    u40.z = hi ? whi[4] : whi[0];
    u40.w = hi ? whi[5] : whi[1];
    u41.x = hi ? wlo[6] : wlo[2];
    u41.y = hi ? wlo[7] : wlo[3];
    u41.z = hi ? whi[6] : whi[2];
    u41.w = hi ? whi[7] : whi[3];
    const int e0 = hi * 2;
    if (ot == 0) {
      char* p = qd2 + ((size_t)b * HW + n) * 64;
      *(uint4*)(p + e0 * 16) = u40;
      *(uint4*)(p + (e0 + 1) * 16) = u41;
    } else if (ot == 1) {
      char* p = kd2 + ((size_t)(b * 64 + tt)) * 4096 + ((n & 63) >> 5) * 2048 + (n & 31) * 16;
      *(uint4*)(p + e0 * 512) = u40;
      *(uint4*)(p + (e0 + 1) * 512) = u41;
    } else {
      int c = ((ot - 2) << 5) + lo5;
      int oct0 = wv * 4;
      char* p = vpd2 + ((size_t)(b * 64 + tt)) * 8192 + (c >> 5) * 4096 + (c & 31) * 16;
      *(uint4*)(p + (oct0 + e0) * 512) = u40;
      *(uint4*)(p + (oct0 + e0 + 1) * 512) = u41;
    }
  }
}

// ---------------- gram: per-wave partial G = X X^T, split-x (h+l) bf16 MFMA ----------------
__global__ __launch_bounds__(128) void gram_kernel(const float* __restrict__ x,
                                                   float* __restrict__ Gp) {
  const int bx = blockIdx.x;
  const int b = bx >> 4, ch = bx & 15;
  const int t = threadIdx.x;
  const int wv = t >> 6, l = t & 63, lo5 = l & 31, hi = l >> 5;
  const int n0 = ch * 256 + wv * 128;
  const float* xb = x + (size_t)b * C * HW;
  f32x16 fz;
#pragma unroll
  for (int r = 0; r < 16; ++r) fz[r] = 0.f;
  f32x16 a00 = fz, a01 = fz, a10 = fz, a11 = fz;
#pragma unroll 1
  for (int kc = 0; kc < 8; ++kc) {
    int nb = n0 + kc * 16 + hi * 8;
    const float4* p0 = (const float4*)(xb + (size_t)lo5 * HW + nb);
    const float4* p1 = (const float4*)(xb + (size_t)(32 + lo5) * HW + nb);
    float v0[8], v1[8];
    {
      float4 a = p0[0], bq = p0[1];
      v0[0] = a.x; v0[1] = a.y; v0[2] = a.z; v0[3] = a.w;
      v0[4] = bq.x; v0[5] = bq.y; v0[6] = bq.z; v0[7] = bq.w;
      float4 c = p1[0], d = p1[1];
      v1[0] = c.x; v1[1] = c.y; v1[2] = c.z; v1[3] = c.w;
      v1[4] = d.x; v1[5] = d.y; v1[6] = d.z; v1[7] = d.w;
    }
    uint4 uh0, ul0, uh1, ul1;
    {
      float h[8], e[8];
#pragma unroll
      for (int j = 0; j < 8; ++j) { h[j] = (float)(__bf16)v0[j]; e[j] = v0[j] - h[j]; }
      uh0.x = pk2(h[0], h[1]); uh0.y = pk2(h[2], h[3]); uh0.z = pk2(h[4], h[5]); uh0.w = pk2(h[6], h[7]);
      ul0.x = cvtpk(e[0], e[1]); ul0.y = cvtpk(e[2], e[3]); ul0.z = cvtpk(e[4], e[5]); ul0.w = cvtpk(e[6], e[7]);
#pragma unroll
      for (int j = 0; j < 8; ++j) { h[j] = (float)(__bf16)v1[j]; e[j] = v1[j] - h[j]; }
      uh1.x = pk2(h[0], h[1]); uh1.y = pk2(h[2], h[3]); uh1.z = pk2(h[4], h[5]); uh1.w = pk2(h[6], h[7]);
      ul1.x = cvtpk(e[0], e[1]); ul1.y = cvtpk(e[2], e[3]); ul1.z = cvtpk(e[4], e[5]); ul1.w = cvtpk(e[6], e[7]);
    }
    bf16x8 f0h = __builtin_bit_cast(bf16x8, uh0);
    bf16x8 f0l = __builtin_bit_cast(bf16x8, ul0);
    bf16x8 f1h = __builtin_bit_cast(bf16x8, uh1);
    bf16x8 f1l = __builtin_bit_cast(bf16x8, ul1);
    a00 = mfma_bf16(f0h, f0h, a00); a00 = mfma_bf16(f0h, f0l, a00); a00 = mfma_bf16(f0l, f0h, a00);
    a01 = mfma_bf16(f0h, f1h, a01); a01 = mfma_bf16(f0h, f1l, a01); a01 = mfma_bf16(f0l, f1h, a01);
    a10 = mfma_bf16(f1h, f0h, a10); a10 = mfma_bf16(f1h, f0l, a10); a10 = mfma_bf16(f1l, f0h, a10);
    a11 = mfma_bf16(f1h, f1h, a11); a11 = mfma_bf16(f1h, f1l, a11); a11 = mfma_bf16(f1l, f1h, a11);
  }
  float* g = Gp + (size_t)(bx * 2 + wv) * 4096;
#pragma unroll
  for (int r = 0; r < 16; ++r) {
    int row = (r & 3) + 8 * (r >> 2) + 4 * hi;
    g[row * 64 + lo5] = a00[r];
    g[row * 64 + 32 + lo5] = a01[r];
    g[(32 + row) * 64 + lo5] = a10[r];
    g[(32 + row) * 64 + 32 + lo5] = a11[r];
  }
}

// ---------------- CAM: reduce G, E = Wc G Wc^T, softmax, M1 = w_bn1 @ attn ([d][o]) ----------------
__global__ __launch_bounds__(256) void cam_m1_kernel(const float* __restrict__ Gp,
                                                     const float* __restrict__ w_cam,
                                                     const float* __restrict__ w_bn,
                                                     float* __restrict__ m1) {
  __shared__ float gs[4096];
  __shared__ float ts[4096];
  __shared__ float wcs[4096];
  __shared__ float wts[4096];
  const int b = blockIdx.x, t = threadIdx.x;
#pragma unroll
  for (int i = 0; i < 16; ++i) {
    int idx = t + i * 256;
    float s = 0.f;
    for (int s32 = 0; s32 < 32; ++s32)
      s += Gp[(size_t)(b * 32 + s32) * 4096 + idx];
    gs[idx] = s;
  }
  float4* wcl = (float4*)wcs;
  const float4* wc4 = (const float4*)w_cam;
#pragma unroll
  for (int i = 0; i < 4; ++i) wcl[t + i * 256] = wc4[t + i * 256];
  __syncthreads();
#pragma unroll
  for (int i = 0; i < 16; ++i) {
    int idx = t + i * 256;
    int r = idx >> 6, d = idx & 63;
    wts[d * 64 + r] = wcs[r * 64 + d];
  }
  __syncthreads();
  const int lane = t & 63, rg = (t >> 6) * 16;
  float acc[16];
#pragma unroll
  for (int r = 0; r < 16; ++r) acc[r] = 0.f;
  for (int c = 0; c < 64; ++c) {
    float g = gs[c * 64 + lane];
#pragma unroll
    for (int r = 0; r < 16; ++r) acc[r] += wcs[(rg + r) * 64 + c] * g;
  }
#pragma unroll
  for (int r = 0; r < 16; ++r) ts[(rg + r) * 64 + lane] = acc[r];
  __syncthreads();
#pragma unroll
  for (int r = 0; r < 16; ++r) acc[r] = 0.f;
  for (int d = 0; d < 64; ++d) {
    float w = wts[d * 64 + lane];
#pragma unroll
    for (int r = 0; r < 16; ++r) acc[r] += ts[(rg + r) * 64 + d] * w;
  }
  __syncthreads();
#pragma unroll
  for (int r = 0; r < 16; ++r) gs[(rg + r) * 64 + lane] = acc[r];
  __syncthreads();
  if (t < 64) {
    float row[64], mx = -1e30f;
#pragma unroll
    for (int d = 0; d < 64; ++d) { row[d] = gs[t * 64 + d]; mx = fmaxf(mx, row[d]); }
    float sum = 0.f;
#pragma unroll
    for (int d = 0; d < 64; ++d) { row[d] = __expf(row[d] - mx); sum += row[d]; }
    float inv = 1.f / sum;
#pragma unroll
    for (int d = 0; d < 64; ++d) wcs[t * 64 + d] = row[d] * inv;
  }
#pragma unroll
  for (int i = 0; i < 16; ++i) {
    int idx = t + i * 256;
    int o = idx & 63, r = idx >> 6;
    wts[r * 64 + o] = w_bn[o * 128 + r];
  }
  __syncthreads();
  float a2[16];
#pragma unroll
  for (int dd = 0; dd < 16; ++dd) a2[dd] = 0.f;
  for (int r = 0; r < 64; ++r) {
    float wv = wts[r * 64 + lane];
#pragma unroll
    for (int dd = 0; dd < 16; ++dd) a2[dd] += wv * wcs[r * 64 + rg + dd];
  }
  float* mb = m1 + (size_t)b * 4096;
#pragma unroll
  for (int dd = 0; dd < 16; ++dd) mb[(rg + dd) * 64 + lane] = a2[dd];
}

// ---------------- SAM flash attention: QB=128, 4-way cross-block KV split ----------------
__global__ __launch_bounds__(256) void fa_kernel(const char* __restrict__ qd2,
                                                 const char* __restrict__ kd2,
                                                 const char* __restrict__ vpd2,
                                                 char* __restrict__ op,
                                                 float* __restrict__ lp) {
  __shared__ __align__(16) char smem[24576];
  const int t = threadIdx.x;
  const int l = t & 63, lo5 = l & 31, hi = l >> 5;
  const int wv = t >> 6;
  const int bx = blockIdx.x;
  const int g = (bx & 7) | ((bx >> 8) << 3);
  const int qt = (bx >> 3) & 31;
  const int b = g >> 2, kvs = g & 3;
  const int nq = qt * 128 + wv * 32 + lo5;

  const char* qb = qd2 + ((size_t)b * HW + nq) * 64;
  bf16x8 qf0 = *(const bf16x8*)(qb + hi * 16);
  bf16x8 qf1 = *(const bf16x8*)(qb + 32 + hi * 16);

  f32x16 fz;
#pragma unroll
  for (int r = 0; r < 16; ++r) fz[r] = 0.f;
  f32x16 o0 = fz, o1 = fz;
  float lrun = 0.f;

  const size_t kb0 = ((size_t)(b * 64 + kvs * 16)) * 4096;
  const size_t vb0 = ((size_t)(b * 64 + kvs * 16)) * 8192;

  auto stage = [&](int it) {
    char* dstb = smem + (it & 1) * 12288;
#pragma unroll
    for (int ss = 0; ss < 3; ++ss) {
      int s = wv * 3 + ss;
      const char* gsrc = (s < 4) ? (kd2 + kb0 + (size_t)it * 4096 + s * 1024)
                                 : (vpd2 + vb0 + (size_t)it * 8192 + (s - 4) * 1024);
      gload_lds16(gsrc + l * 16, dstb + s * 1024);
    }
  };

  stage(0);
  asm volatile("s_waitcnt vmcnt(0)" ::: "memory");
  __syncthreads();

#pragma unroll 1
  for (int i = 0; i < 16; ++i) {
    if (i < 15) stage(i + 1);
    const char* kb = smem + (i & 1) * 12288;
    const char* vb = kb + 4096;
    bf16x8 kf00 = *(const bf16x8*)(kb + l * 16);
    bf16x8 kf01 = *(const bf16x8*)(kb + 1024 + l * 16);
    bf16x8 kf10 = *(const bf16x8*)(kb + 2048 + l * 16);
    bf16x8 kf11 = *(const bf16x8*)(kb + 3072 + l * 16);
    f32x16 s0 = mfma_bf16(kf00, qf0, fz);
    s0 = mfma_bf16(kf01, qf1, s0);
    f32x16 s1 = mfma_bf16(kf10, qf0, fz);
    s1 = mfma_bf16(kf11, qf1, s1);
    bf16x8 vfa[4], vfb[4];
#pragma unroll
    for (int ks = 0; ks < 4; ++ks) {
      vfa[ks] = *(const bf16x8*)(vb + ks * 1024 + l * 16);
      vfb[ks] = *(const bf16x8*)(vb + 4096 + ks * 1024 + l * 16);
    }
    float ps = 0.f;
#pragma unroll
    for (int r = 0; r < 16; ++r) {
      s0[r] = __builtin_amdgcn_exp2f(s0[r]);
      ps += s0[r];
    }
#pragma unroll
    for (int r = 0; r < 16; ++r) {
      s1[r] = __builtin_amdgcn_exp2f(s1[r]);
      ps += s1[r];
    }
    ps += __shfl_xor(ps, 32);
    lrun += ps;
#pragma unroll
    for (int ks = 0; ks < 4; ++ks) {
      const f32x16& pm = (ks < 2) ? s0 : s1;
      const int rb = (ks & 1) * 8;
      uint w0 = cvtpk(pm[rb + 0], pm[rb + 1]);
      uint w1 = cvtpk(pm[rb + 2], pm[rb + 3]);
      uint w2 = cvtpk(pm[rb + 4], pm[rb + 5]);
      uint w3 = cvtpk(pm[rb + 6], pm[rb + 7]);
      uint x0 = __shfl_xor(w0, 32);
      uint x1 = __shfl_xor(w1, 32);
      uint x2 = __shfl_xor(w2, 32);
      uint x3 = __shfl_xor(w3, 32);
      uint4 fw;
      fw.x = hi ? x2 : w0;
      fw.y = hi ? x3 : w1;
      fw.z = hi ? w2 : x0;
      fw.w = hi ? w3 : x1;
      bf16x8 pf = __builtin_bit_cast(bf16x8, fw);
      o0 = mfma_bf16(vfa[ks], pf, o0);
      o1 = mfma_bf16(vfb[ks], pf, o1);
    }
    asm volatile("s_waitcnt vmcnt(0)" ::: "memory");
    __syncthreads();
  }

  ushort* opu = (ushort*)op;
  const size_t obase = ((size_t)(b * 64) * 4 + kvs) * HW + nq;
#pragma unroll
  for (int r = 0; r < 16; ++r) {
    int c0 = (r & 3) + 8 * (r >> 2) + 4 * hi;
    opu[obase + (size_t)c0 * 4 * HW] = bfb(o0[r]);
    opu[obase + (size_t)(c0 + 32) * 4 * HW] = bfb(o1[r]);
  }
  if (hi == 0) lp[(size_t)(kvs * 8 + b) * HW + nq] = lrun;
}

// ---------------- epilogue: out = x + M1@x + merge(op)/merge(l) ----------------
__global__ __launch_bounds__(256) void final_kernel(const float* __restrict__ x,
                                                    const float* __restrict__ m1,
                                                    const char* __restrict__ op,
                                                    const float* __restrict__ lp,
                                                    float* __restrict__ outp) {
  __shared__ __align__(16) float xt[4096];
  __shared__ __align__(16) float ms[4096];
  const int b = blockIdx.y, tt = blockIdx.x, t = threadIdx.x;
  const float4* xg = (const float4*)(x + (size_t)b * C * HW);
  float4* xt4 = (float4*)xt;
#pragma unroll
  for (int i = 0; i < 4; ++i) {
    int idx = t + i * 256;
    int c = idx >> 4, ng = idx & 15;
    xt4[c * 16 + (ng ^ (c & 15))] = xg[c * 1024 + tt * 16 + ng];
  }
  float4* ms4 = (float4*)ms;
  const float4* mg = (const float4*)(m1 + (size_t)b * 4096);
#pragma unroll
  for (int i = 0; i < 4; ++i) ms4[t + i * 256] = mg[t + i * 256];
  __syncthreads();
  const int n = t & 63, sub = t >> 6;
  const int gn = tt * 64 + n;
  float xr[64];
#pragma unroll
  for (int c = 0; c < 64; ++c)
    xr[c] = xt[c * 64 + (((n >> 2) ^ (c & 15)) << 2) + (n & 3)];
  float lsum = 0.f;
#pragma unroll
  for (int kvs = 0; kvs < 4; ++kvs) lsum += lp[(size_t)(kvs * 8 + b) * HW + gn];
  float linv = 1.f / lsum;
  const ushort* opu = (const ushort*)op;
  float acc[16];
#pragma unroll
  for (int ci = 0; ci < 16; ++ci) {
    int c = sub * 16 + ci;
    float osum = 0.f;
#pragma unroll
    for (int kvs = 0; kvs < 4; ++kvs) {
      ushort u = opu[((size_t)(b * 64 + c) * 4 + kvs) * HW + gn];
      osum += __builtin_bit_cast(float, (uint)u << 16);
    }
    acc[ci] = xr[c] + osum * linv;
  }
  for (int d = 0; d < 64; ++d) {
    float xv = xr[d];
    const float4* mr = (const float4*)(ms + d * 64 + sub * 16);
#pragma unroll
    for (int c4 = 0; c4 < 4; ++c4) {
      float4 mv = mr[c4];
      acc[c4 * 4 + 0] += mv.x * xv;
      acc[c4 * 4 + 1] += mv.y * xv;
      acc[c4 * 4 + 2] += mv.z * xv;
      acc[c4 * 4 + 3] += mv.w * xv;
    }
  }
  float* ob = outp + (size_t)b * C * HW + gn;
#pragma unroll
  for (int ci = 0; ci < 16; ++ci)
    ob[(size_t)(sub * 16 + ci) * HW] = acc[ci];
}

extern "C" void kernel_launch(void* const* d_in, const int* in_sizes, int n_in,
                              void* d_out, int out_size, void* d_ws, size_t ws_size,
                              hipStream_t stream) {
  const float* x     = (const float*)d_in[0];
  const float* w_cam = (const float*)d_in[1];
  const float* w_q   = (const float*)d_in[2];
  const float* w_k   = (const float*)d_in[3];
  const float* w_v   = (const float*)d_in[4];
  const float* w_bn  = (const float*)d_in[5];
  float* out = (float*)d_out;
  char* wsb = (char*)d_ws;

  // workspace layout (bytes)
  char*  wall = wsb;                               // 16 KB  wall fragments
  float* m1   = (float*)(wsb + 16384);             // 128 KB
  char*  qd2  = wsb + 147456;                      // 2 MB
  char*  kd2  = qd2 + 2097152;                     // 2 MB
  char*  vpd2 = kd2 + 2097152;                     // 4 MB
  float* lp   = (float*)(vpd2 + 4194304);          // 512 KB
  char*  un   = (char*)lp + 524288;                // 16 MB union: Gp (4MB) then op
  float* Gp   = (float*)un;
  char*  op   = un;

  fold_kernel<<<16, 64, 0, stream>>>(w_bn, w_q, w_k, w_v, wall);
  prep_kernel<<<512, 128, 0, stream>>>(x, wall, qd2, kd2, vpd2);
  gram_kernel<<<128, 128, 0, stream>>>(x, Gp);
  cam_m1_kernel<<<8, 256, 0, stream>>>(Gp, w_cam, w_bn, m1);
  fa_kernel<<<1024, 256, 0, stream>>>(qd2, kd2, vpd2, op, lp);
  final_kernel<<<dim3(64, BB), 256, 0, stream>>>(x, m1, op, lp, out);
}